// Round 1
// baseline (5192.658 us; speedup 1.0000x reference)
//
#include <hip/hip_runtime.h>
#include <hip/hip_fp16.h>

#define N_NODES 4096
#define DIMS 128

static constexpr float BIGF = 1e9f;
static constexpr float EPSF = 1e-12f;

// ---------------- helpers ----------------

template<typename DT> __device__ inline DT to_dt(float v);
template<> __device__ inline float  to_dt<float>(float v)  { return v; }
template<> __device__ inline __half to_dt<__half>(float v) { return __float2half(v); }

__device__ inline void load_row16(const float* __restrict__ p, float* v) {
    const float4* q = (const float4*)p;
    float4 a = q[0], b = q[1], c = q[2], d = q[3];
    v[0]=a.x; v[1]=a.y; v[2]=a.z; v[3]=a.w;
    v[4]=b.x; v[5]=b.y; v[6]=b.z; v[7]=b.w;
    v[8]=c.x; v[9]=c.y; v[10]=c.z; v[11]=c.w;
    v[12]=d.x; v[13]=d.y; v[14]=d.z; v[15]=d.w;
}

__device__ inline void load_row16(const __half* __restrict__ p, float* v) {
    const __half2* q = (const __half2*)p;
    #pragma unroll
    for (int i = 0; i < 8; i++) {
        float2 f = __half22float2(q[i]);
        v[2*i] = f.x; v[2*i+1] = f.y;
    }
}

__device__ inline unsigned long long shfl_xor_u64(unsigned long long v, int m) {
    int lo = __shfl_xor((int)(unsigned)(v & 0xFFFFFFFFull), m);
    int hi = __shfl_xor((int)(unsigned)(v >> 32), m);
    return ((unsigned long long)(unsigned)hi << 32) | (unsigned)lo;
}

// block must be exactly 256 threads; returns full sum to all threads
__device__ inline float block_reduce_sum_256(float v) {
    __shared__ float s[4];
    __syncthreads();
    #pragma unroll
    for (int off = 32; off; off >>= 1) v += __shfl_xor(v, off);
    if ((threadIdx.x & 63) == 0) s[threadIdx.x >> 6] = v;
    __syncthreads();
    return s[0] + s[1] + s[2] + s[3];
}

// ---------------- distance matrix ----------------
// D[i][j] = sqrt(max(sum_k (X[i][k]-X[j][k])^2, EPS))
// 32x32 output tile per 256-thread block, 2x2 register blocking.
template<typename DT>
__global__ __launch_bounds__(256) void dist_kernel(const float* __restrict__ X,
                                                   DT* __restrict__ D) {
    __shared__ float As[32][DIMS + 1];
    __shared__ float Bs[32][DIMS + 1];
    const int bi = blockIdx.y * 32;
    const int bj = blockIdx.x * 32;
    const int t  = threadIdx.x;

    #pragma unroll
    for (int p = 0; p < 4; p++) {
        int f = t + p * 256;        // float4 id, 0..1023
        int r = f >> 5;             // row 0..31
        int c = (f & 31) << 2;      // col 0..124
        float4 va = *(const float4*)&X[(size_t)(bi + r) * DIMS + c];
        As[r][c] = va.x; As[r][c+1] = va.y; As[r][c+2] = va.z; As[r][c+3] = va.w;
        float4 vb = *(const float4*)&X[(size_t)(bj + r) * DIMS + c];
        Bs[r][c] = vb.x; Bs[r][c+1] = vb.y; Bs[r][c+2] = vb.z; Bs[r][c+3] = vb.w;
    }
    __syncthreads();

    const int tx = t & 15, ty = t >> 4;
    float acc00 = 0.f, acc01 = 0.f, acc10 = 0.f, acc11 = 0.f;
    #pragma unroll 8
    for (int k = 0; k < DIMS; k++) {
        float a0 = As[ty][k],      a1 = As[ty + 16][k];
        float b0 = Bs[tx][k],      b1 = Bs[tx + 16][k];
        float d;
        d = a0 - b0; acc00 += d * d;
        d = a0 - b1; acc01 += d * d;
        d = a1 - b0; acc10 += d * d;
        d = a1 - b1; acc11 += d * d;
    }
    D[(size_t)(bi + ty)      * N_NODES + bj + tx]      = to_dt<DT>(sqrtf(fmaxf(acc00, EPSF)));
    D[(size_t)(bi + ty)      * N_NODES + bj + tx + 16] = to_dt<DT>(sqrtf(fmaxf(acc01, EPSF)));
    D[(size_t)(bi + ty + 16) * N_NODES + bj + tx]      = to_dt<DT>(sqrtf(fmaxf(acc10, EPSF)));
    D[(size_t)(bi + ty + 16) * N_NODES + bj + tx + 16] = to_dt<DT>(sqrtf(fmaxf(acc11, EPSF)));
}

// ---------------- Prim MST + bitonic sort ----------------
// grid = 2 blocks (block 0: student, block 1: teacher), 256 threads each.
// Each thread owns 16 nodes: dist[] in registers, visited as 16-bit mask.
template<typename DT>
__global__ __launch_bounds__(256) void prim_kernel(const DT* __restrict__ Dst,
                                                   const DT* __restrict__ Dte,
                                                   float* __restrict__ deaths_s,
                                                   float* __restrict__ deaths_t) {
    const DT* D = (blockIdx.x == 0) ? Dst : Dte;
    float* deaths_out = (blockIdx.x == 0) ? deaths_s : deaths_t;

    __shared__ float s_vals[N_NODES];              // MST weights, then sorted
    __shared__ unsigned long long s_red[4];
    __shared__ unsigned long long s_win;

    const int t = threadIdx.x;
    const int base = t << 4;

    float dist[16];
    load_row16(D + base, dist);                    // row 0
    unsigned visited = (t == 0) ? 1u : 0u;         // node 0 visited

    for (int it = 0; it < N_NODES - 1; ++it) {
        // local argmin over owned nodes, packed (float bits << 32) | idx
        unsigned long long best = 0xFFFFFFFFFFFFFFFFull;
        #pragma unroll
        for (int k = 0; k < 16; k++) {
            float v = ((visited >> k) & 1u) ? BIGF : dist[k];
            unsigned long long key =
                ((unsigned long long)__float_as_uint(v) << 32) | (unsigned)(base + k);
            best = (key < best) ? key : best;
        }
        // wave reduce
        #pragma unroll
        for (int m = 32; m; m >>= 1) {
            unsigned long long o = shfl_xor_u64(best, m);
            best = (o < best) ? o : best;
        }
        if ((t & 63) == 0) s_red[t >> 6] = best;
        __syncthreads();
        if (t == 0) {
            unsigned long long w = s_red[0];
            if (s_red[1] < w) w = s_red[1];
            if (s_red[2] < w) w = s_red[2];
            if (s_red[3] < w) w = s_red[3];
            s_win = w;
            s_vals[it] = __uint_as_float((unsigned)(w >> 32));
        }
        __syncthreads();
        const unsigned long long w = s_win;
        const int j = (int)(w & 0xFFFFFFFFu);
        if ((j >> 4) == t) visited |= 1u << (j & 15);
        // update dist from row j
        float row[16];
        load_row16(D + (size_t)j * N_NODES + base, row);
        #pragma unroll
        for (int k = 0; k < 16; k++) dist[k] = fminf(dist[k], row[k]);
    }

    __syncthreads();
    if (t == 0) s_vals[N_NODES - 1] = BIGF;        // pad slot 4095
    __syncthreads();

    // bitonic ascending sort of s_vals[0..4095]
    for (int k = 2; k <= N_NODES; k <<= 1) {
        for (int j2 = k >> 1; j2 > 0; j2 >>= 1) {
            for (int i = t; i < N_NODES; i += 256) {
                int p = i ^ j2;
                if (p > i) {
                    float a = s_vals[i], b = s_vals[p];
                    bool asc = (i & k) == 0;
                    if ((a > b) == asc) { s_vals[i] = b; s_vals[p] = a; }
                }
            }
            __syncthreads();
        }
    }

    for (int i = t; i < N_NODES - 1; i += 256) deaths_out[i] = s_vals[i];
}

// ---------------- repr loss partials ----------------
__global__ __launch_bounds__(256) void repr_partial_kernel(const float* __restrict__ S,
                                                           const float* __restrict__ T,
                                                           float* __restrict__ partials) {
    const int tid = blockIdx.x * 256 + threadIdx.x;
    const int stride = gridDim.x * 256;
    const float4* S4 = (const float4*)S;
    const float4* T4 = (const float4*)T;
    float acc = 0.f;
    for (int i = tid; i < (N_NODES * DIMS) / 4; i += stride) {
        float4 a = S4[i], b = T4[i];
        float dx = a.x - b.x, dy = a.y - b.y, dz = a.z - b.z, dw = a.w - b.w;
        acc += dx * dx + dy * dy + dz * dz + dw * dw;
    }
    float s = block_reduce_sum_256(acc);
    if (threadIdx.x == 0) partials[blockIdx.x] = s;
}

// ---------------- finalize ----------------
__global__ __launch_bounds__(256) void finalize_kernel(const float* __restrict__ ds,
                                                       const float* __restrict__ dt,
                                                       const float* __restrict__ partials,
                                                       int n_partials,
                                                       float* __restrict__ out) {
    float a = 0.f;
    for (int i = threadIdx.x; i < N_NODES - 1; i += 256) {
        float d = ds[i] - dt[i];
        a += d * d;
    }
    float topo_sum = block_reduce_sum_256(a);
    float r = 0.f;
    for (int i = threadIdx.x; i < n_partials; i += 256) r += partials[i];
    float repr_sum = block_reduce_sum_256(r);
    if (threadIdx.x == 0) {
        float repr = repr_sum / (float)(N_NODES * DIMS);
        float topo = topo_sum / (float)(2 * (N_NODES - 1));
        out[0] = 0.5f * repr + 0.5f * topo;
        out[1] = repr;
        out[2] = topo;
    }
}

// ---------------- host ----------------

template<typename DT>
static void run_path(const float* S, const float* T, float* out, char* ws,
                     hipStream_t stream) {
    const size_t nn = (size_t)N_NODES * N_NODES;
    DT* Ds = (DT*)ws;
    DT* Dt = (DT*)(ws + nn * sizeof(DT));
    float* deaths_s = (float*)(ws + 2 * nn * sizeof(DT));
    float* deaths_t = deaths_s + N_NODES;
    float* partials = deaths_t + N_NODES;

    dim3 dg(N_NODES / 32, N_NODES / 32);
    dist_kernel<DT><<<dg, 256, 0, stream>>>(S, Ds);
    dist_kernel<DT><<<dg, 256, 0, stream>>>(T, Dt);
    repr_partial_kernel<<<256, 256, 0, stream>>>(S, T, partials);
    prim_kernel<DT><<<2, 256, 0, stream>>>(Ds, Dt, deaths_s, deaths_t);
    finalize_kernel<<<1, 256, 0, stream>>>(deaths_s, deaths_t, partials, 256, out);
}

extern "C" void kernel_launch(void* const* d_in, const int* in_sizes, int n_in,
                              void* d_out, int out_size, void* d_ws, size_t ws_size,
                              hipStream_t stream) {
    const float* S = (const float*)d_in[0];
    const float* T = (const float*)d_in[1];
    float* out = (float*)d_out;
    char* ws = (char*)d_ws;

    const size_t nn = (size_t)N_NODES * N_NODES;
    const size_t extras = (2 * N_NODES + 256 + 64) * sizeof(float);
    if (ws_size >= 2 * nn * sizeof(float) + extras) {
        run_path<float>(S, T, out, ws, stream);
    } else {
        run_path<__half>(S, T, out, ws, stream);
    }
}

// Round 2
// 849.801 us; speedup vs baseline: 6.1104x; 6.1104x over previous
//
#include <hip/hip_runtime.h>
#include <hip/hip_fp16.h>

#define N_NODES 4096
#define DIMS 128

static constexpr float BIGF = 1e9f;
static constexpr float EPSF = 1e-12f;
static constexpr unsigned long long KEY_INF = ~0ull;

// ---------------- helpers ----------------

template<typename DT> __device__ inline DT to_dt(float v);
template<> __device__ inline float  to_dt<float>(float v)  { return v; }
template<> __device__ inline __half to_dt<__half>(float v) { return __float2half(v); }

// load 4 consecutive cols as float
__device__ inline void load_cols4(const float* __restrict__ p, float* w) {
    float4 v = *(const float4*)p;
    w[0] = v.x; w[1] = v.y; w[2] = v.z; w[3] = v.w;
}
__device__ inline void load_cols4(const __half* __restrict__ p, float* w) {
    const __half2* q = (const __half2*)p;
    float2 a = __half22float2(q[0]), b = __half22float2(q[1]);
    w[0] = a.x; w[1] = a.y; w[2] = b.x; w[3] = b.y;
}

__device__ inline unsigned long long shfl_xor_u64(unsigned long long v, int m) {
    int lo = __shfl_xor((int)(unsigned)(v & 0xFFFFFFFFull), m);
    int hi = __shfl_xor((int)(unsigned)(v >> 32), m);
    return ((unsigned long long)(unsigned)hi << 32) | (unsigned)lo;
}

__device__ inline unsigned long long u64min(unsigned long long a, unsigned long long b) {
    return a < b ? a : b;
}

// block must be exactly 256 threads; returns full sum to all threads
__device__ inline float block_reduce_sum_256(float v) {
    __shared__ float s[4];
    __syncthreads();
    #pragma unroll
    for (int off = 32; off; off >>= 1) v += __shfl_xor(v, off);
    if ((threadIdx.x & 63) == 0) s[threadIdx.x >> 6] = v;
    __syncthreads();
    return s[0] + s[1] + s[2] + s[3];
}

// ---------------- distance matrix ----------------
// D[i][j] = sqrt(max(sum_k (X[i][k]-X[j][k])^2, EPS))
// Bitwise symmetric: identical accumulation order for (i,j) and (j,i).
template<typename DT>
__global__ __launch_bounds__(256) void dist_kernel(const float* __restrict__ X,
                                                   DT* __restrict__ D) {
    __shared__ float As[32][DIMS + 1];
    __shared__ float Bs[32][DIMS + 1];
    const int bi = blockIdx.y * 32;
    const int bj = blockIdx.x * 32;
    const int t  = threadIdx.x;

    #pragma unroll
    for (int p = 0; p < 4; p++) {
        int f = t + p * 256;        // float4 id, 0..1023
        int r = f >> 5;             // row 0..31
        int c = (f & 31) << 2;      // col 0..124
        float4 va = *(const float4*)&X[(size_t)(bi + r) * DIMS + c];
        As[r][c] = va.x; As[r][c+1] = va.y; As[r][c+2] = va.z; As[r][c+3] = va.w;
        float4 vb = *(const float4*)&X[(size_t)(bj + r) * DIMS + c];
        Bs[r][c] = vb.x; Bs[r][c+1] = vb.y; Bs[r][c+2] = vb.z; Bs[r][c+3] = vb.w;
    }
    __syncthreads();

    const int tx = t & 15, ty = t >> 4;
    float acc00 = 0.f, acc01 = 0.f, acc10 = 0.f, acc11 = 0.f;
    #pragma unroll 8
    for (int k = 0; k < DIMS; k++) {
        float a0 = As[ty][k],      a1 = As[ty + 16][k];
        float b0 = Bs[tx][k],      b1 = Bs[tx + 16][k];
        float d;
        d = a0 - b0; acc00 += d * d;
        d = a0 - b1; acc01 += d * d;
        d = a1 - b0; acc10 += d * d;
        d = a1 - b1; acc11 += d * d;
    }
    D[(size_t)(bi + ty)      * N_NODES + bj + tx]      = to_dt<DT>(sqrtf(fmaxf(acc00, EPSF)));
    D[(size_t)(bi + ty)      * N_NODES + bj + tx + 16] = to_dt<DT>(sqrtf(fmaxf(acc01, EPSF)));
    D[(size_t)(bi + ty + 16) * N_NODES + bj + tx]      = to_dt<DT>(sqrtf(fmaxf(acc10, EPSF)));
    D[(size_t)(bi + ty + 16) * N_NODES + bj + tx + 16] = to_dt<DT>(sqrtf(fmaxf(acc11, EPSF)));
}

// ---------------- Boruvka MST ----------------
// Edge order: strict total order on (weight_bits, canonical_edge_id) packed as
// key = (w_bits << 24) | (min(i,j)<<12 | max(i,j)).  MST unique => matches Prim.

__global__ __launch_bounds__(1024) void init_kernel(unsigned* __restrict__ comp,
                                                    unsigned long long* __restrict__ best_comp,
                                                    unsigned* __restrict__ cnt) {
    int i = blockIdx.x * 1024 + threadIdx.x;
    if (i < 2 * N_NODES) {
        comp[i] = (unsigned)(i & (N_NODES - 1));
        best_comp[i] = KEY_INF;
    }
    if (i < 2) cnt[i] = 0;
}

// grid = (N_NODES/16, 2), block = 256 (4 waves); each wave scans 4 rows.
template<typename DT>
__global__ __launch_bounds__(256) void boruvka_scan(const DT* __restrict__ D0,
                                                    const DT* __restrict__ D1,
                                                    const unsigned* __restrict__ comp,
                                                    unsigned long long* __restrict__ best_node,
                                                    unsigned long long* __restrict__ best_comp) {
    const int m = blockIdx.y;
    const DT* __restrict__ D = m ? D1 : D0;
    const unsigned* __restrict__ cm = comp + m * N_NODES;
    unsigned long long* bn = best_node + m * N_NODES;
    unsigned long long* bc = best_comp + m * N_NODES;

    __shared__ unsigned s_comp[N_NODES];
    for (int i = threadIdx.x; i < N_NODES; i += 256) s_comp[i] = cm[i];
    __syncthreads();

    const int wave = threadIdx.x >> 6, lane = threadIdx.x & 63;
    const int rbase = blockIdx.x * 16 + wave * 4;

    for (int rr = 0; rr < 4; rr++) {
        const int r = rbase + rr;
        const unsigned ci = s_comp[r];
        unsigned long long best = KEY_INF;
        const DT* row = D + (size_t)r * N_NODES;
        #pragma unroll 4
        for (int it = 0; it < N_NODES / 256; it++) {
            int c0 = it * 256 + lane * 4;
            float w[4];
            load_cols4(row + c0, w);
            #pragma unroll
            for (int u = 0; u < 4; u++) {
                int j = c0 + u;
                if (s_comp[j] != ci) {
                    unsigned a = (unsigned)min(r, j), b = (unsigned)max(r, j);
                    unsigned canon = (a << 12) | b;
                    unsigned long long key =
                        ((unsigned long long)__float_as_uint(w[u]) << 24) | canon;
                    best = u64min(best, key);
                }
            }
        }
        #pragma unroll
        for (int s = 32; s; s >>= 1) best = u64min(best, shfl_xor_u64(best, s));
        if (lane == 0) {
            bn[r] = best;
            if (best != KEY_INF) atomicMin(&bc[ci], best);
        }
    }
}

// grid = 2 blocks (one per matrix), 1024 threads.
__global__ __launch_bounds__(1024) void boruvka_merge(unsigned* __restrict__ comp,
                                                      const unsigned long long* __restrict__ best_node,
                                                      unsigned long long* __restrict__ best_comp,
                                                      float* __restrict__ deaths,
                                                      unsigned* __restrict__ cnt) {
    const int m = blockIdx.x;
    unsigned* cm = comp + m * N_NODES;
    const unsigned long long* bn = best_node + m * N_NODES;
    unsigned long long* bc = best_comp + m * N_NODES;
    float* dth = deaths + m * N_NODES;

    __shared__ unsigned s_comp[N_NODES];
    __shared__ unsigned s_par[N_NODES];
    __shared__ unsigned long long s_bc[N_NODES];

    const int t = threadIdx.x;
    for (int i = t; i < N_NODES; i += 1024) {
        s_comp[i] = cm[i];
        s_par[i]  = (unsigned)i;
        s_bc[i]   = bc[i];
    }
    __syncthreads();

    // winner per component hooks; append edge once (dedupe mutual pairs)
    for (int i = t; i < N_NODES; i += 1024) {
        unsigned long long k = bn[i];
        unsigned ci = s_comp[i];
        if (k != KEY_INF && k == s_bc[ci]) {
            unsigned canon = (unsigned)(k & 0xFFFFFFu);
            unsigned a = canon >> 12, b = canon & 0xFFFu;
            unsigned j = (a == (unsigned)i) ? b : a;
            unsigned cj = s_comp[j];
            s_par[ci] = cj;                       // unique winner per comp: no race
            bool mutual = (s_bc[cj] == k);
            if (!mutual || ci < cj) {
                unsigned idx = atomicAdd(&cnt[m], 1u);
                dth[idx] = __uint_as_float((unsigned)(k >> 24));
            }
        }
    }
    __syncthreads();

    // break 2-cycles: smaller id becomes root
    unsigned nv[4];
    #pragma unroll
    for (int q = 0; q < 4; q++) {
        int i = t + q * 1024;
        unsigned p = s_par[i], pp = s_par[p];
        nv[q] = (pp == (unsigned)i) ? ((unsigned)i < p ? (unsigned)i : p) : p;
    }
    __syncthreads();
    #pragma unroll
    for (int q = 0; q < 4; q++) s_par[t + q * 1024] = nv[q];
    __syncthreads();

    // pointer jumping (depth <= 4096 -> 12 halvings)
    for (int r = 0; r < 12; r++) {
        #pragma unroll
        for (int q = 0; q < 4; q++) nv[q] = s_par[s_par[t + q * 1024]];
        __syncthreads();
        #pragma unroll
        for (int q = 0; q < 4; q++) s_par[t + q * 1024] = nv[q];
        __syncthreads();
    }

    // relabel nodes; reset per-component best for next round
    for (int i = t; i < N_NODES; i += 1024) {
        cm[i] = s_par[s_comp[i]];
        bc[i] = KEY_INF;
    }
}

// ---------------- sort (bitonic, in LDS) ----------------
__global__ __launch_bounds__(1024) void sort_kernel(float* __restrict__ deaths) {
    float* d = deaths + blockIdx.x * N_NODES;
    __shared__ float s[N_NODES];
    const int t = threadIdx.x;
    for (int i = t; i < N_NODES - 1; i += 1024) s[i] = d[i];
    if (t == 0) s[N_NODES - 1] = BIGF;
    __syncthreads();
    for (int k = 2; k <= N_NODES; k <<= 1) {
        for (int j = k >> 1; j > 0; j >>= 1) {
            for (int i = t; i < N_NODES; i += 1024) {
                int p = i ^ j;
                if (p > i) {
                    float a = s[i], b = s[p];
                    bool asc = (i & k) == 0;
                    if ((a > b) == asc) { s[i] = b; s[p] = a; }
                }
            }
            __syncthreads();
        }
    }
    for (int i = t; i < N_NODES - 1; i += 1024) d[i] = s[i];
}

// ---------------- repr loss partials ----------------
__global__ __launch_bounds__(256) void repr_partial_kernel(const float* __restrict__ S,
                                                           const float* __restrict__ T,
                                                           float* __restrict__ partials) {
    const int tid = blockIdx.x * 256 + threadIdx.x;
    const int stride = gridDim.x * 256;
    const float4* S4 = (const float4*)S;
    const float4* T4 = (const float4*)T;
    float acc = 0.f;
    for (int i = tid; i < (N_NODES * DIMS) / 4; i += stride) {
        float4 a = S4[i], b = T4[i];
        float dx = a.x - b.x, dy = a.y - b.y, dz = a.z - b.z, dw = a.w - b.w;
        acc += dx * dx + dy * dy + dz * dz + dw * dw;
    }
    float s = block_reduce_sum_256(acc);
    if (threadIdx.x == 0) partials[blockIdx.x] = s;
}

// ---------------- finalize ----------------
__global__ __launch_bounds__(256) void finalize_kernel(const float* __restrict__ deaths,
                                                       const float* __restrict__ partials,
                                                       int n_partials,
                                                       float* __restrict__ out) {
    const float* ds = deaths;
    const float* dt = deaths + N_NODES;
    float a = 0.f;
    for (int i = threadIdx.x; i < N_NODES - 1; i += 256) {
        float d = ds[i] - dt[i];
        a += d * d;
    }
    float topo_sum = block_reduce_sum_256(a);
    float r = 0.f;
    for (int i = threadIdx.x; i < n_partials; i += 256) r += partials[i];
    float repr_sum = block_reduce_sum_256(r);
    if (threadIdx.x == 0) {
        float repr = repr_sum / (float)(N_NODES * DIMS);
        float topo = topo_sum / (float)(2 * (N_NODES - 1));
        out[0] = 0.5f * repr + 0.5f * topo;
        out[1] = repr;
        out[2] = topo;
    }
}

// ---------------- host ----------------

template<typename DT>
static void run_path(const float* S, const float* T, float* out, char* ws,
                     hipStream_t stream) {
    const size_t nn = (size_t)N_NODES * N_NODES;
    DT* Ds = (DT*)ws;
    DT* Dt = (DT*)(ws + nn * sizeof(DT));
    char* p = ws + 2 * nn * sizeof(DT);
    // 8-byte-aligned extras first
    unsigned long long* best_node = (unsigned long long*)p;  p += 2 * N_NODES * 8;
    unsigned long long* best_comp = (unsigned long long*)p;  p += 2 * N_NODES * 8;
    float*    deaths   = (float*)p;     p += 2 * N_NODES * 4;
    unsigned* comp     = (unsigned*)p;  p += 2 * N_NODES * 4;
    float*    partials = (float*)p;     p += 256 * 4;
    unsigned* cnt      = (unsigned*)p;

    dim3 dg(N_NODES / 32, N_NODES / 32);
    dist_kernel<DT><<<dg, 256, 0, stream>>>(S, Ds);
    dist_kernel<DT><<<dg, 256, 0, stream>>>(T, Dt);
    repr_partial_kernel<<<256, 256, 0, stream>>>(S, T, partials);

    init_kernel<<<(2 * N_NODES + 1023) / 1024, 1024, 0, stream>>>(comp, best_comp, cnt);
    dim3 sg(N_NODES / 16, 2);
    for (int r = 0; r < 12; r++) {
        boruvka_scan<DT><<<sg, 256, 0, stream>>>(Ds, Dt, comp, best_node, best_comp);
        boruvka_merge<<<2, 1024, 0, stream>>>(comp, best_node, best_comp, deaths, cnt);
    }
    sort_kernel<<<2, 1024, 0, stream>>>(deaths);
    finalize_kernel<<<1, 256, 0, stream>>>(deaths, partials, 256, out);
}

extern "C" void kernel_launch(void* const* d_in, const int* in_sizes, int n_in,
                              void* d_out, int out_size, void* d_ws, size_t ws_size,
                              hipStream_t stream) {
    const float* S = (const float*)d_in[0];
    const float* T = (const float*)d_in[1];
    float* out = (float*)d_out;
    char* ws = (char*)d_ws;

    const size_t nn = (size_t)N_NODES * N_NODES;
    const size_t extras = (size_t)2 * N_NODES * (8 + 8 + 4 + 4) + 256 * 4 + 64;
    if (ws_size >= 2 * nn * sizeof(float) + extras) {
        run_path<float>(S, T, out, ws, stream);
    } else {
        run_path<__half>(S, T, out, ws, stream);
    }
}

// Round 3
// 502.186 us; speedup vs baseline: 10.3401x; 1.6922x over previous
//
#include <hip/hip_runtime.h>
#include <hip/hip_fp16.h>

#define N_NODES 4096
#define DIMS 128

static constexpr float BIGF = 1e9f;
static constexpr float EPSF = 1e-12f;
static constexpr unsigned long long KEY_INF = ~0ull;

// ---------------- helpers ----------------

__device__ inline void store4(float* p, float a, float b, float c, float d) {
    *(float4*)p = make_float4(a, b, c, d);
}
__device__ inline void store4(__half* p, float a, float b, float c, float d) {
    __half2* q = (__half2*)p;
    q[0] = __floats2half2_rn(a, b);
    q[1] = __floats2half2_rn(c, d);
}

__device__ inline void load_cols4(const float* __restrict__ p, float* w) {
    float4 v = *(const float4*)p;
    w[0] = v.x; w[1] = v.y; w[2] = v.z; w[3] = v.w;
}
__device__ inline void load_cols4(const __half* __restrict__ p, float* w) {
    const __half2* q = (const __half2*)p;
    float2 a = __half22float2(q[0]), b = __half22float2(q[1]);
    w[0] = a.x; w[1] = a.y; w[2] = b.x; w[3] = b.y;
}

__device__ inline unsigned long long shfl_xor_u64(unsigned long long v, int m) {
    int lo = __shfl_xor((int)(unsigned)(v & 0xFFFFFFFFull), m);
    int hi = __shfl_xor((int)(unsigned)(v >> 32), m);
    return ((unsigned long long)(unsigned)hi << 32) | (unsigned)lo;
}

__device__ inline unsigned long long u64min(unsigned long long a, unsigned long long b) {
    return a < b ? a : b;
}

__device__ inline float block_reduce_sum_256(float v) {
    __shared__ float s[4];
    __syncthreads();
    #pragma unroll
    for (int off = 32; off; off >>= 1) v += __shfl_xor(v, off);
    if ((threadIdx.x & 63) == 0) s[threadIdx.x >> 6] = v;
    __syncthreads();
    return s[0] + s[1] + s[2] + s[3];
}

// ---------------- distance matrix ----------------
// 64x64 tile, 4x4 register blocking, K staged in two 64-wide chunks.
// Accumulation order (k ascending, sequential adds) is bitwise symmetric
// and identical to the previous round's kernel.
template<typename DT>
__global__ __launch_bounds__(256) void dist_kernel(const float* __restrict__ X,
                                                   DT* __restrict__ D) {
    __shared__ float As[64][66];   // stride%8==2: broadcast-row reads spread
    __shared__ float Bs[64][65];   // odd stride: 16 distinct-row reads spread
    const int bi = blockIdx.y * 64;
    const int bj = blockIdx.x * 64;
    const int t  = threadIdx.x;
    const int tx = t & 15, ty = t >> 4;

    float acc[4][4];
    #pragma unroll
    for (int u = 0; u < 4; u++)
        #pragma unroll
        for (int v = 0; v < 4; v++) acc[u][v] = 0.f;

    for (int kc = 0; kc < 2; kc++) {
        const int k0 = kc * 64;
        __syncthreads();
        #pragma unroll
        for (int p = 0; p < 4; p++) {
            int f  = t + p * 256;
            int r  = f >> 4;
            int c4 = (f & 15) << 2;
            float4 va = *(const float4*)&X[(size_t)(bi + r) * DIMS + k0 + c4];
            As[r][c4] = va.x; As[r][c4+1] = va.y; As[r][c4+2] = va.z; As[r][c4+3] = va.w;
            float4 vb = *(const float4*)&X[(size_t)(bj + r) * DIMS + k0 + c4];
            Bs[r][c4] = vb.x; Bs[r][c4+1] = vb.y; Bs[r][c4+2] = vb.z; Bs[r][c4+3] = vb.w;
        }
        __syncthreads();

        #pragma unroll 2
        for (int k4 = 0; k4 < 64; k4 += 4) {
            float4 av[4], bv[4];
            #pragma unroll
            for (int u = 0; u < 4; u++) av[u] = *(const float4*)&As[4 * ty + u][k4];
            #pragma unroll
            for (int v = 0; v < 4; v++) bv[v] = *(const float4*)&Bs[4 * tx + v][k4];
            #pragma unroll
            for (int u = 0; u < 4; u++)
                #pragma unroll
                for (int v = 0; v < 4; v++) {
                    float d0 = av[u].x - bv[v].x;
                    float d1 = av[u].y - bv[v].y;
                    float d2 = av[u].z - bv[v].z;
                    float d3 = av[u].w - bv[v].w;
                    float s = acc[u][v];
                    s += d0 * d0; s += d1 * d1; s += d2 * d2; s += d3 * d3;
                    acc[u][v] = s;
                }
        }
    }

    #pragma unroll
    for (int u = 0; u < 4; u++) {
        int row = bi + 4 * ty + u;
        store4(&D[(size_t)row * N_NODES + bj + 4 * tx],
               sqrtf(fmaxf(acc[u][0], EPSF)),
               sqrtf(fmaxf(acc[u][1], EPSF)),
               sqrtf(fmaxf(acc[u][2], EPSF)),
               sqrtf(fmaxf(acc[u][3], EPSF)));
    }
}

// ---------------- Boruvka MST ----------------

__global__ __launch_bounds__(1024) void init_kernel(unsigned* __restrict__ comp,
                                                    unsigned long long* __restrict__ best_comp,
                                                    unsigned* __restrict__ cnt,
                                                    unsigned* __restrict__ done) {
    int i = blockIdx.x * 1024 + threadIdx.x;
    if (i < 2 * N_NODES) {
        comp[i] = (unsigned)(i & (N_NODES - 1));
        best_comp[i] = KEY_INF;
    }
    if (i < 2) { cnt[i] = 0; done[i] = 0; }
}

template<typename DT>
__global__ __launch_bounds__(256) void boruvka_scan(const DT* __restrict__ D0,
                                                    const DT* __restrict__ D1,
                                                    const unsigned* __restrict__ comp,
                                                    unsigned long long* __restrict__ best_node,
                                                    unsigned long long* __restrict__ best_comp,
                                                    const unsigned* __restrict__ done) {
    const int m = blockIdx.y;
    if (done[m]) return;
    const DT* __restrict__ D = m ? D1 : D0;
    const unsigned* __restrict__ cm = comp + m * N_NODES;
    unsigned long long* bn = best_node + m * N_NODES;
    unsigned long long* bc = best_comp + m * N_NODES;

    __shared__ unsigned s_comp[N_NODES];
    for (int i = threadIdx.x; i < N_NODES; i += 256) s_comp[i] = cm[i];
    __syncthreads();

    const int wave = threadIdx.x >> 6, lane = threadIdx.x & 63;
    const int rbase = blockIdx.x * 16 + wave * 4;

    for (int rr = 0; rr < 4; rr++) {
        const int r = rbase + rr;
        const unsigned ci = s_comp[r];
        unsigned long long best = KEY_INF;
        const DT* row = D + (size_t)r * N_NODES;
        #pragma unroll 4
        for (int it = 0; it < N_NODES / 256; it++) {
            int c0 = it * 256 + lane * 4;
            float w[4];
            load_cols4(row + c0, w);
            #pragma unroll
            for (int u = 0; u < 4; u++) {
                int j = c0 + u;
                if (s_comp[j] != ci) {
                    unsigned a = (unsigned)min(r, j), b = (unsigned)max(r, j);
                    unsigned canon = (a << 12) | b;
                    unsigned long long key =
                        ((unsigned long long)__float_as_uint(w[u]) << 24) | canon;
                    best = u64min(best, key);
                }
            }
        }
        #pragma unroll
        for (int s = 32; s; s >>= 1) best = u64min(best, shfl_xor_u64(best, s));
        if (lane == 0) {
            bn[r] = best;
            if (best != KEY_INF) atomicMin(&bc[ci], best);
        }
    }
}

__global__ __launch_bounds__(1024) void boruvka_merge(unsigned* __restrict__ comp,
                                                      const unsigned long long* __restrict__ best_node,
                                                      unsigned long long* __restrict__ best_comp,
                                                      float* __restrict__ deaths,
                                                      unsigned* __restrict__ cnt,
                                                      unsigned* __restrict__ done) {
    const int m = blockIdx.x;
    if (done[m]) return;
    unsigned* cm = comp + m * N_NODES;
    const unsigned long long* bn = best_node + m * N_NODES;
    unsigned long long* bc = best_comp + m * N_NODES;
    float* dth = deaths + m * N_NODES;

    __shared__ unsigned s_comp[N_NODES];
    __shared__ unsigned s_par[N_NODES];
    __shared__ unsigned long long s_bc[N_NODES];

    const int t = threadIdx.x;
    for (int i = t; i < N_NODES; i += 1024) {
        s_comp[i] = cm[i];
        s_par[i]  = (unsigned)i;
        s_bc[i]   = bc[i];
    }
    __syncthreads();

    for (int i = t; i < N_NODES; i += 1024) {
        unsigned long long k = bn[i];
        unsigned ci = s_comp[i];
        if (k != KEY_INF && k == s_bc[ci]) {
            unsigned canon = (unsigned)(k & 0xFFFFFFu);
            unsigned a = canon >> 12, b = canon & 0xFFFu;
            unsigned j = (a == (unsigned)i) ? b : a;
            unsigned cj = s_comp[j];
            s_par[ci] = cj;
            bool mutual = (s_bc[cj] == k);
            if (!mutual || ci < cj) {
                unsigned idx = atomicAdd(&cnt[m], 1u);
                dth[idx] = __uint_as_float((unsigned)(k >> 24));
            }
        }
    }
    __syncthreads();

    unsigned nv[4];
    #pragma unroll
    for (int q = 0; q < 4; q++) {
        int i = t + q * 1024;
        unsigned p = s_par[i], pp = s_par[p];
        nv[q] = (pp == (unsigned)i) ? ((unsigned)i < p ? (unsigned)i : p) : p;
    }
    __syncthreads();
    #pragma unroll
    for (int q = 0; q < 4; q++) s_par[t + q * 1024] = nv[q];
    __syncthreads();

    for (int r = 0; r < 12; r++) {
        #pragma unroll
        for (int q = 0; q < 4; q++) nv[q] = s_par[s_par[t + q * 1024]];
        __syncthreads();
        #pragma unroll
        for (int q = 0; q < 4; q++) s_par[t + q * 1024] = nv[q];
        __syncthreads();
    }

    for (int i = t; i < N_NODES; i += 1024) {
        cm[i] = s_par[s_comp[i]];
        bc[i] = KEY_INF;
    }
    __syncthreads();
    if (t == 0) {
        unsigned c = atomicAdd(&cnt[m], 0u);
        if (c >= N_NODES - 1) done[m] = 1u;
    }
}

// ---------------- sort (bitonic, in LDS) ----------------
__global__ __launch_bounds__(1024) void sort_kernel(float* __restrict__ deaths) {
    float* d = deaths + blockIdx.x * N_NODES;
    __shared__ float s[N_NODES];
    const int t = threadIdx.x;
    for (int i = t; i < N_NODES - 1; i += 1024) s[i] = d[i];
    if (t == 0) s[N_NODES - 1] = BIGF;
    __syncthreads();
    for (int k = 2; k <= N_NODES; k <<= 1) {
        for (int j = k >> 1; j > 0; j >>= 1) {
            for (int i = t; i < N_NODES; i += 1024) {
                int p = i ^ j;
                if (p > i) {
                    float a = s[i], b = s[p];
                    bool asc = (i & k) == 0;
                    if ((a > b) == asc) { s[i] = b; s[p] = a; }
                }
            }
            __syncthreads();
        }
    }
    for (int i = t; i < N_NODES - 1; i += 1024) d[i] = s[i];
}

// ---------------- repr loss partials ----------------
__global__ __launch_bounds__(256) void repr_partial_kernel(const float* __restrict__ S,
                                                           const float* __restrict__ T,
                                                           float* __restrict__ partials) {
    const int tid = blockIdx.x * 256 + threadIdx.x;
    const int stride = gridDim.x * 256;
    const float4* S4 = (const float4*)S;
    const float4* T4 = (const float4*)T;
    float acc = 0.f;
    for (int i = tid; i < (N_NODES * DIMS) / 4; i += stride) {
        float4 a = S4[i], b = T4[i];
        float dx = a.x - b.x, dy = a.y - b.y, dz = a.z - b.z, dw = a.w - b.w;
        acc += dx * dx + dy * dy + dz * dz + dw * dw;
    }
    float s = block_reduce_sum_256(acc);
    if (threadIdx.x == 0) partials[blockIdx.x] = s;
}

// ---------------- finalize ----------------
__global__ __launch_bounds__(256) void finalize_kernel(const float* __restrict__ deaths,
                                                       const float* __restrict__ partials,
                                                       int n_partials,
                                                       float* __restrict__ out) {
    const float* ds = deaths;
    const float* dt = deaths + N_NODES;
    float a = 0.f;
    for (int i = threadIdx.x; i < N_NODES - 1; i += 256) {
        float d = ds[i] - dt[i];
        a += d * d;
    }
    float topo_sum = block_reduce_sum_256(a);
    float r = 0.f;
    for (int i = threadIdx.x; i < n_partials; i += 256) r += partials[i];
    float repr_sum = block_reduce_sum_256(r);
    if (threadIdx.x == 0) {
        float repr = repr_sum / (float)(N_NODES * DIMS);
        float topo = topo_sum / (float)(2 * (N_NODES - 1));
        out[0] = 0.5f * repr + 0.5f * topo;
        out[1] = repr;
        out[2] = topo;
    }
}

// ---------------- host ----------------

template<typename DT>
static void run_path(const float* S, const float* T, float* out, char* ws,
                     hipStream_t stream) {
    const size_t nn = (size_t)N_NODES * N_NODES;
    DT* Ds = (DT*)ws;
    DT* Dt = (DT*)(ws + nn * sizeof(DT));
    char* p = ws + 2 * nn * sizeof(DT);
    unsigned long long* best_node = (unsigned long long*)p;  p += 2 * N_NODES * 8;
    unsigned long long* best_comp = (unsigned long long*)p;  p += 2 * N_NODES * 8;
    float*    deaths   = (float*)p;     p += 2 * N_NODES * 4;
    unsigned* comp     = (unsigned*)p;  p += 2 * N_NODES * 4;
    float*    partials = (float*)p;     p += 256 * 4;
    unsigned* cnt      = (unsigned*)p;  p += 2 * 4;
    unsigned* done     = (unsigned*)p;

    dim3 dg(N_NODES / 64, N_NODES / 64);
    dist_kernel<DT><<<dg, 256, 0, stream>>>(S, Ds);
    dist_kernel<DT><<<dg, 256, 0, stream>>>(T, Dt);
    repr_partial_kernel<<<256, 256, 0, stream>>>(S, T, partials);

    init_kernel<<<(2 * N_NODES + 1023) / 1024, 1024, 0, stream>>>(comp, best_comp, cnt, done);
    dim3 sg(N_NODES / 16, 2);
    for (int r = 0; r < 12; r++) {
        boruvka_scan<DT><<<sg, 256, 0, stream>>>(Ds, Dt, comp, best_node, best_comp, done);
        boruvka_merge<<<2, 1024, 0, stream>>>(comp, best_node, best_comp, deaths, cnt, done);
    }
    sort_kernel<<<2, 1024, 0, stream>>>(deaths);
    finalize_kernel<<<1, 256, 0, stream>>>(deaths, partials, 256, out);
}

extern "C" void kernel_launch(void* const* d_in, const int* in_sizes, int n_in,
                              void* d_out, int out_size, void* d_ws, size_t ws_size,
                              hipStream_t stream) {
    const float* S = (const float*)d_in[0];
    const float* T = (const float*)d_in[1];
    float* out = (float*)d_out;
    char* ws = (char*)d_ws;

    const size_t nn = (size_t)N_NODES * N_NODES;
    const size_t extras = (size_t)2 * N_NODES * (8 + 8 + 4 + 4) + 256 * 4 + 64;
    if (ws_size >= 2 * nn * sizeof(float) + extras) {
        run_path<float>(S, T, out, ws, stream);
    } else {
        run_path<__half>(S, T, out, ws, stream);
    }
}

// Round 4
// 315.701 us; speedup vs baseline: 16.4480x; 1.5907x over previous
//
#include <hip/hip_runtime.h>
#include <hip/hip_fp16.h>

#define N_NODES 4096
#define DIMS 128

typedef __attribute__((ext_vector_type(8))) short short8;
typedef __attribute__((ext_vector_type(4))) float f32x4;

static constexpr float BIGF = 1e9f;
static constexpr float EPSF = 1e-12f;
static constexpr unsigned long long KEY_INF = ~0ull;

// ---------------- helpers ----------------

__device__ inline unsigned short f32_to_bf16(float f) {
    unsigned u = __float_as_uint(f);
    unsigned r = (u + 0x7FFFu + ((u >> 16) & 1u)) >> 16;   // RNE
    return (unsigned short)r;
}

__device__ inline unsigned long long shfl_xor_u64(unsigned long long v, int m) {
    int lo = __shfl_xor((int)(unsigned)(v & 0xFFFFFFFFull), m);
    int hi = __shfl_xor((int)(unsigned)(v >> 32), m);
    return ((unsigned long long)(unsigned)hi << 32) | (unsigned)lo;
}

__device__ inline unsigned long long u64min(unsigned long long a, unsigned long long b) {
    return a < b ? a : b;
}

__device__ inline float block_reduce_sum_256(float v) {
    __shared__ float s[4];
    __syncthreads();
    #pragma unroll
    for (int off = 32; off; off >>= 1) v += __shfl_xor(v, off);
    if ((threadIdx.x & 63) == 0) s[threadIdx.x >> 6] = v;
    __syncthreads();
    return s[0] + s[1] + s[2] + s[3];
}

// ---------------- prep: X -> bf16, row norms ----------------
// grid 512 x 256: block handles 8 rows; each half-wave (32 lanes) one row.
__global__ __launch_bounds__(256) void prep_kernel(const float* __restrict__ X,
                                                   unsigned short* __restrict__ X16,
                                                   float* __restrict__ sq) {
    const int t = threadIdx.x;
    const int wave = t >> 6, lane = t & 63;
    const int row = blockIdx.x * 8 + wave * 2 + (lane >> 5);
    const int c4 = (lane & 31) * 4;
    float4 v = *(const float4*)&X[(size_t)row * DIMS + c4];
    float ss = v.x * v.x + v.y * v.y + v.z * v.z + v.w * v.w;
    #pragma unroll
    for (int m = 16; m; m >>= 1) ss += __shfl_xor(ss, m);   // reduce within 32
    if ((lane & 31) == 0) sq[row] = ss;
    ushort4 o;
    o.x = f32_to_bf16(v.x); o.y = f32_to_bf16(v.y);
    o.z = f32_to_bf16(v.z); o.w = f32_to_bf16(v.w);
    *(ushort4*)&X16[(size_t)row * DIMS + c4] = o;
}

// ---------------- distance matrix via MFMA ----------------
// 64x64 tile, 4 waves; wave w computes rows [16w,16w+16) x cols [0,64).
// D[i][j] = sqrt(max(sq_i + sq_j - 2*G_ij, EPS)) stored fp16.
// G via bf16 16x16x32 MFMA; A/B packed with the same lane->k mapping, so the
// Gram is correct under any hardware k-permutation. C/D: col=lane&15,
// row=(lane>>4)*4+reg (m89/m91-verified). G symmetric bitwise -> D symmetric.
__global__ __launch_bounds__(256) void dist_kernel(const unsigned short* __restrict__ X16,
                                                   const float* __restrict__ sq,
                                                   __half* __restrict__ D) {
    __shared__ __align__(16) unsigned short Abuf[64 * 128];
    __shared__ __align__(16) unsigned short Bbuf[64 * 128];
    const int bi = blockIdx.y * 64;
    const int bj = blockIdx.x * 64;
    const int t = threadIdx.x;

    // stage both operands, XOR-swizzled 16B chunks (slot = c8 ^ (r&7))
    #pragma unroll
    for (int p = 0; p < 4; p++) {
        int f = t + p * 256;          // 0..1023
        int r = f >> 4, c8 = f & 15;
        int slot = c8 ^ (r & 7);
        uint4 va = *(const uint4*)&X16[(size_t)(bi + r) * DIMS + c8 * 8];
        *(uint4*)&Abuf[r * 128 + slot * 8] = va;
        uint4 vb = *(const uint4*)&X16[(size_t)(bj + r) * DIMS + c8 * 8];
        *(uint4*)&Bbuf[r * 128 + slot * 8] = vb;
    }
    __syncthreads();

    const int wave = t >> 6, lane = t & 63;
    const int l15 = lane & 15, kg = lane >> 4;

    // A fragments for 4 k-steps (reused across 4 col-frags)
    const int rowA = wave * 16 + l15;
    short8 afrag[4];
    #pragma unroll
    for (int s = 0; s < 4; s++) {
        int c8 = s * 4 + kg;
        int slot = c8 ^ (rowA & 7);
        afrag[s] = *(const short8*)&Abuf[rowA * 128 + slot * 8];
    }

    f32x4 acc[4] = {};
    #pragma unroll
    for (int n = 0; n < 4; n++) {
        const int rowB = n * 16 + l15;
        #pragma unroll
        for (int s = 0; s < 4; s++) {
            int c8 = s * 4 + kg;
            int slot = c8 ^ (rowB & 7);
            short8 bfrag = *(const short8*)&Bbuf[rowB * 128 + slot * 8];
            acc[n] = __builtin_amdgcn_mfma_f32_16x16x32_bf16(afrag[s], bfrag, acc[n], 0, 0, 0);
        }
    }

    // epilogue
    const int r0 = wave * 16 + kg * 4;
    float sqi[4];
    #pragma unroll
    for (int rr = 0; rr < 4; rr++) sqi[rr] = sq[bi + r0 + rr];
    #pragma unroll
    for (int n = 0; n < 4; n++) {
        const int col = bj + n * 16 + l15;
        const float sqj = sq[col];
        #pragma unroll
        for (int rr = 0; rr < 4; rr++) {
            float d2 = sqi[rr] + sqj - 2.0f * acc[n][rr];
            float dd = sqrtf(fmaxf(d2, EPSF));
            D[(size_t)(bi + r0 + rr) * N_NODES + col] = __float2half(dd);
        }
    }
}

// ---------------- Boruvka MST ----------------
// key = (w_bits << 24) | (min(i,j)<<12 | max(i,j)) -- strict total order,
// unique MST, deaths multiset matches Prim.

__global__ __launch_bounds__(1024) void init_kernel(unsigned* __restrict__ comp,
                                                    unsigned long long* __restrict__ best_comp,
                                                    unsigned* __restrict__ cnt,
                                                    unsigned* __restrict__ done) {
    int i = blockIdx.x * 1024 + threadIdx.x;
    if (i < 2 * N_NODES) {
        comp[i] = (unsigned)(i & (N_NODES - 1));
        best_comp[i] = KEY_INF;
    }
    if (i < 2) { cnt[i] = 0; done[i] = 0; }
}

// grid = (N_NODES/16, 2), block = 256 (4 waves); each wave scans 4 rows,
// 8 fp16 cols per lane per iteration.
__global__ __launch_bounds__(256) void boruvka_scan(const __half* __restrict__ D0,
                                                    const __half* __restrict__ D1,
                                                    const unsigned* __restrict__ comp,
                                                    unsigned long long* __restrict__ best_node,
                                                    unsigned long long* __restrict__ best_comp,
                                                    const unsigned* __restrict__ done) {
    const int m = blockIdx.y;
    if (done[m]) return;
    const __half* __restrict__ D = m ? D1 : D0;
    const unsigned* __restrict__ cm = comp + m * N_NODES;
    unsigned long long* bn = best_node + m * N_NODES;
    unsigned long long* bc = best_comp + m * N_NODES;

    __shared__ unsigned s_comp[N_NODES];
    for (int i = threadIdx.x; i < N_NODES; i += 256) s_comp[i] = cm[i];
    __syncthreads();

    const int wave = threadIdx.x >> 6, lane = threadIdx.x & 63;
    const int rbase = blockIdx.x * 16 + wave * 4;

    for (int rr = 0; rr < 4; rr++) {
        const int r = rbase + rr;
        const unsigned ci = s_comp[r];
        unsigned long long best = KEY_INF;
        const __half* row = D + (size_t)r * N_NODES;
        #pragma unroll 2
        for (int it = 0; it < 8; it++) {
            int c0 = it * 512 + lane * 8;
            uint4 raw = *(const uint4*)&row[c0];
            float w[8];
            {
                float2 f;
                f = __half22float2(*(const __half2*)&raw.x); w[0] = f.x; w[1] = f.y;
                f = __half22float2(*(const __half2*)&raw.y); w[2] = f.x; w[3] = f.y;
                f = __half22float2(*(const __half2*)&raw.z); w[4] = f.x; w[5] = f.y;
                f = __half22float2(*(const __half2*)&raw.w); w[6] = f.x; w[7] = f.y;
            }
            #pragma unroll
            for (int u = 0; u < 8; u++) {
                int j = c0 + u;
                if (s_comp[j] != ci) {
                    unsigned a = (unsigned)min(r, j), b = (unsigned)max(r, j);
                    unsigned canon = (a << 12) | b;
                    unsigned long long key =
                        ((unsigned long long)__float_as_uint(w[u]) << 24) | canon;
                    best = u64min(best, key);
                }
            }
        }
        #pragma unroll
        for (int s = 32; s; s >>= 1) best = u64min(best, shfl_xor_u64(best, s));
        if (lane == 0) {
            bn[r] = best;
            if (best != KEY_INF) atomicMin(&bc[ci], best);
        }
    }
}

// grid = 2 blocks (one per matrix), 1024 threads.
__global__ __launch_bounds__(1024) void boruvka_merge(unsigned* __restrict__ comp,
                                                      const unsigned long long* __restrict__ best_node,
                                                      unsigned long long* __restrict__ best_comp,
                                                      float* __restrict__ deaths,
                                                      unsigned* __restrict__ cnt,
                                                      unsigned* __restrict__ done) {
    const int m = blockIdx.x;
    if (done[m]) return;
    unsigned* cm = comp + m * N_NODES;
    const unsigned long long* bn = best_node + m * N_NODES;
    unsigned long long* bc = best_comp + m * N_NODES;
    float* dth = deaths + m * N_NODES;

    __shared__ unsigned s_comp[N_NODES];
    __shared__ unsigned s_par[N_NODES];
    __shared__ unsigned long long s_bc[N_NODES];
    __shared__ int s_changed;

    const int t = threadIdx.x;
    for (int i = t; i < N_NODES; i += 1024) {
        s_comp[i] = cm[i];
        s_par[i]  = (unsigned)i;
        s_bc[i]   = bc[i];
    }
    __syncthreads();

    // winner per component hooks; append edge once (dedupe mutual pairs)
    for (int i = t; i < N_NODES; i += 1024) {
        unsigned long long k = bn[i];
        unsigned ci = s_comp[i];
        if (k != KEY_INF && k == s_bc[ci]) {
            unsigned canon = (unsigned)(k & 0xFFFFFFu);
            unsigned a = canon >> 12, b = canon & 0xFFFu;
            unsigned j = (a == (unsigned)i) ? b : a;
            unsigned cj = s_comp[j];
            s_par[ci] = cj;                       // unique winner per comp
            bool mutual = (s_bc[cj] == k);
            if (!mutual || ci < cj) {
                unsigned idx = atomicAdd(&cnt[m], 1u);
                dth[idx] = __uint_as_float((unsigned)(k >> 24));
            }
        }
    }
    __syncthreads();

    // break 2-cycles: smaller id becomes root
    unsigned nv[4], pv[4];
    #pragma unroll
    for (int q = 0; q < 4; q++) {
        int i = t + q * 1024;
        unsigned p = s_par[i], pp = s_par[p];
        nv[q] = (pp == (unsigned)i) ? ((unsigned)i < p ? (unsigned)i : p) : p;
    }
    __syncthreads();
    #pragma unroll
    for (int q = 0; q < 4; q++) s_par[t + q * 1024] = nv[q];
    __syncthreads();

    // pointer jumping with convergence check
    for (;;) {
        bool ch = false;
        #pragma unroll
        for (int q = 0; q < 4; q++) {
            pv[q] = s_par[t + q * 1024];
            nv[q] = s_par[pv[q]];
            ch |= (nv[q] != pv[q]);
        }
        if (t == 0) s_changed = 0;
        __syncthreads();
        if (ch) s_changed = 1;
        #pragma unroll
        for (int q = 0; q < 4; q++) s_par[t + q * 1024] = nv[q];
        __syncthreads();
        if (!s_changed) break;
    }

    // relabel nodes; reset per-component best for next round
    for (int i = t; i < N_NODES; i += 1024) {
        cm[i] = s_par[s_comp[i]];
        bc[i] = KEY_INF;
    }
    __syncthreads();
    if (t == 0) {
        unsigned c = atomicAdd(&cnt[m], 0u);
        if (c >= N_NODES - 1) done[m] = 1u;
    }
}

// ---------------- sort (bitonic, in LDS) ----------------
__global__ __launch_bounds__(1024) void sort_kernel(float* __restrict__ deaths) {
    float* d = deaths + blockIdx.x * N_NODES;
    __shared__ float s[N_NODES];
    const int t = threadIdx.x;
    for (int i = t; i < N_NODES - 1; i += 1024) s[i] = d[i];
    if (t == 0) s[N_NODES - 1] = BIGF;
    __syncthreads();
    for (int k = 2; k <= N_NODES; k <<= 1) {
        for (int j = k >> 1; j > 0; j >>= 1) {
            for (int i = t; i < N_NODES; i += 1024) {
                int p = i ^ j;
                if (p > i) {
                    float a = s[i], b = s[p];
                    bool asc = (i & k) == 0;
                    if ((a > b) == asc) { s[i] = b; s[p] = a; }
                }
            }
            __syncthreads();
        }
    }
    for (int i = t; i < N_NODES - 1; i += 1024) d[i] = s[i];
}

// ---------------- repr loss partials ----------------
__global__ __launch_bounds__(256) void repr_partial_kernel(const float* __restrict__ S,
                                                           const float* __restrict__ T,
                                                           float* __restrict__ partials) {
    const int tid = blockIdx.x * 256 + threadIdx.x;
    const int stride = gridDim.x * 256;
    const float4* S4 = (const float4*)S;
    const float4* T4 = (const float4*)T;
    float acc = 0.f;
    for (int i = tid; i < (N_NODES * DIMS) / 4; i += stride) {
        float4 a = S4[i], b = T4[i];
        float dx = a.x - b.x, dy = a.y - b.y, dz = a.z - b.z, dw = a.w - b.w;
        acc += dx * dx + dy * dy + dz * dz + dw * dw;
    }
    float s = block_reduce_sum_256(acc);
    if (threadIdx.x == 0) partials[blockIdx.x] = s;
}

// ---------------- finalize ----------------
__global__ __launch_bounds__(256) void finalize_kernel(const float* __restrict__ deaths,
                                                       const float* __restrict__ partials,
                                                       int n_partials,
                                                       float* __restrict__ out) {
    const float* ds = deaths;
    const float* dt = deaths + N_NODES;
    float a = 0.f;
    for (int i = threadIdx.x; i < N_NODES - 1; i += 256) {
        float d = ds[i] - dt[i];
        a += d * d;
    }
    float topo_sum = block_reduce_sum_256(a);
    float r = 0.f;
    for (int i = threadIdx.x; i < n_partials; i += 256) r += partials[i];
    float repr_sum = block_reduce_sum_256(r);
    if (threadIdx.x == 0) {
        float repr = repr_sum / (float)(N_NODES * DIMS);
        float topo = topo_sum / (float)(2 * (N_NODES - 1));
        out[0] = 0.5f * repr + 0.5f * topo;
        out[1] = repr;
        out[2] = topo;
    }
}

// ---------------- host ----------------

extern "C" void kernel_launch(void* const* d_in, const int* in_sizes, int n_in,
                              void* d_out, int out_size, void* d_ws, size_t ws_size,
                              hipStream_t stream) {
    const float* S = (const float*)d_in[0];
    const float* T = (const float*)d_in[1];
    float* out = (float*)d_out;

    const size_t nn = (size_t)N_NODES * N_NODES;
    char* p = (char*)d_ws;
    __half* Ds = (__half*)p;                 p += nn * 2;
    __half* Dt = (__half*)p;                 p += nn * 2;
    unsigned short* X16s = (unsigned short*)p; p += (size_t)N_NODES * DIMS * 2;
    unsigned short* X16t = (unsigned short*)p; p += (size_t)N_NODES * DIMS * 2;
    unsigned long long* best_node = (unsigned long long*)p; p += 2 * N_NODES * 8;
    unsigned long long* best_comp = (unsigned long long*)p; p += 2 * N_NODES * 8;
    float*    sqs      = (float*)p;    p += N_NODES * 4;
    float*    sqt      = (float*)p;    p += N_NODES * 4;
    float*    deaths   = (float*)p;    p += 2 * N_NODES * 4;
    unsigned* comp     = (unsigned*)p; p += 2 * N_NODES * 4;
    float*    partials = (float*)p;    p += 256 * 4;
    unsigned* cnt      = (unsigned*)p; p += 2 * 4;
    unsigned* done     = (unsigned*)p;

    prep_kernel<<<N_NODES / 8, 256, 0, stream>>>(S, X16s, sqs);
    prep_kernel<<<N_NODES / 8, 256, 0, stream>>>(T, X16t, sqt);

    dim3 dg(N_NODES / 64, N_NODES / 64);
    dist_kernel<<<dg, 256, 0, stream>>>(X16s, sqs, Ds);
    dist_kernel<<<dg, 256, 0, stream>>>(X16t, sqt, Dt);

    repr_partial_kernel<<<256, 256, 0, stream>>>(S, T, partials);

    init_kernel<<<(2 * N_NODES + 1023) / 1024, 1024, 0, stream>>>(comp, best_comp, cnt, done);
    dim3 sg(N_NODES / 16, 2);
    for (int r = 0; r < 12; r++) {
        boruvka_scan<<<sg, 256, 0, stream>>>(Ds, Dt, comp, best_node, best_comp, done);
        boruvka_merge<<<2, 1024, 0, stream>>>(comp, best_node, best_comp, deaths, cnt, done);
    }
    sort_kernel<<<2, 1024, 0, stream>>>(deaths);
    finalize_kernel<<<1, 256, 0, stream>>>(deaths, partials, 256, out);
}